// Round 10
// baseline (141.459 us; speedup 1.0000x reference)
//
#include <hip/hip_runtime.h>

#define LRELU_SLOPE 0.2f
#define K_SLAB 40
#define OVF_MAX 8192

// ---------------------------------------------------------------------------
// 4-dispatch gather GAT.
// Round-9 state: all own kernels < 41us (below the harness's 268MB ws-poison
// fill). Residual own cost is k_scatter: 1 edge/thread = single ~300cy
// atomic+write latency chain per lane. Round-10 change: 4 edges/thread ->
// 4 independent chains in flight (ILP), loads stay coalesced.
//
// Kept lessons: no cooperative grid.sync (~100us/barrier, round 6); all
// per-thread arrays statically indexed (scratch demotion, round 8);
// transposed slab colsrc[rank*N+d], K=40 Poisson(8), overflow list for
// correctness (empty in practice).
//
// Workspace: nodef[N float4] | cnt[N] | ovfcnt[1] | colsrc[K*N] |
//            ovfd[OVF_MAX] | ovfs[OVF_MAX]
// ---------------------------------------------------------------------------

// K1: edge pass — 4 edges/thread; rank via atomic count, transposed slab.
__global__ void k_scatter(const int* __restrict__ esrc, const int* __restrict__ edst,
                          int* __restrict__ cnt, int* __restrict__ colsrc,
                          int* __restrict__ ovfcnt, int* __restrict__ ovfd,
                          int* __restrict__ ovfs, float* __restrict__ out,
                          int E, int N) {
    int j = blockIdx.x * blockDim.x + threadIdx.x;
    if (j == 0) { out[0] = 0.f; out[1] = 0.f; }
    int base = j * 4;
    if (base >= E) return;

    int s0, s1, s2, s3, d0, d1, d2, d3;
    int m = E - base;                 // >=1
    // adjacent loads (wave-coalesced); only the last thread diverges
    s0 = esrc[base];     d0 = edst[base];
    s1 = m > 1 ? esrc[base + 1] : 0;  d1 = m > 1 ? edst[base + 1] : 0;
    s2 = m > 2 ? esrc[base + 2] : 0;  d2 = m > 2 ? edst[base + 2] : 0;
    s3 = m > 3 ? esrc[base + 3] : 0;  d3 = m > 3 ? edst[base + 3] : 0;

    // independent atomic chains — overlap their latencies
    int r0 = atomicAdd(&cnt[d0], 1);
    int r1 = m > 1 ? atomicAdd(&cnt[d1], 1) : 0x7fffffff;
    int r2 = m > 2 ? atomicAdd(&cnt[d2], 1) : 0x7fffffff;
    int r3 = m > 3 ? atomicAdd(&cnt[d3], 1) : 0x7fffffff;

    if (r0 < K_SLAB) colsrc[r0 * N + d0] = s0;
    else if (r0 != 0x7fffffff) { int p = atomicAdd(ovfcnt, 1); if (p < OVF_MAX) { ovfd[p] = d0; ovfs[p] = s0; } }
    if (r1 < K_SLAB) colsrc[r1 * N + d1] = s1;
    else if (r1 != 0x7fffffff) { int p = atomicAdd(ovfcnt, 1); if (p < OVF_MAX) { ovfd[p] = d1; ovfs[p] = s1; } }
    if (r2 < K_SLAB) colsrc[r2 * N + d2] = s2;
    else if (r2 != 0x7fffffff) { int p = atomicAdd(ovfcnt, 1); if (p < OVF_MAX) { ovfd[p] = d2; ovfs[p] = s2; } }
    if (r3 < K_SLAB) colsrc[r3 * N + d3] = s3;
    else if (r3 != 0x7fffffff) { int p = atomicAdd(ovfcnt, 1); if (p < OVF_MAX) { ovfd[p] = d3; ovfs[p] = s3; } }
}

// K2: layer-1 gather + rank-1 expansion + ReLU + 512x2 GEMV.
// 8 threads/node. All per-thread arrays statically indexed (h outer,
// fully unrolled) -> registers. float4 LDS reads, static offsets.
// Softmax max-subtraction skipped (shift-invariant, |e| small, fp32 ok).
__global__ __launch_bounds__(256) void k_gather1(
        const int* __restrict__ cnt, const int* __restrict__ colsrc,
        const int* __restrict__ ovfcnt, const int* __restrict__ ovfd,
        const int* __restrict__ ovfs,
        const float* __restrict__ x,
        const float* __restrict__ W1, const float* __restrict__ as1,
        const float* __restrict__ ad1, const float* __restrict__ b1,
        const float* __restrict__ W2, const float* __restrict__ as2,
        const float* __restrict__ ad2,
        float4* __restrict__ nodef, int N) {
    __shared__ float sW1[512], sB1[512], sW2[1024], sconsts[16];
    for (int t = threadIdx.x; t < 512; t += 256) { sW1[t] = W1[t]; sB1[t] = b1[t]; }
    for (int t = threadIdx.x; t < 1024; t += 256) sW2[t] = W2[t];
    if (threadIdx.x < 16) {
        int h = threadIdx.x & 7;
        const float* a = (threadIdx.x < 8) ? as1 : ad1;
        float acc = 0.f;
        #pragma unroll
        for (int f = 0; f < 64; ++f) acc += W1[h * 64 + f] * a[h * 64 + f];
        sconsts[threadIdx.x] = acc;
    }
    __syncthreads();
    int t = blockIdx.x * blockDim.x + threadIdx.x;
    int n = t >> 3, sub = t & 7;
    if (n >= N) return;

    float cs[8], cd[8];
    #pragma unroll
    for (int h = 0; h < 8; ++h) { cs[h] = sconsts[h]; cd[h] = sconsts[8 + h]; }
    float xd = x[n];
    float den[8], num[8];
    #pragma unroll
    for (int h = 0; h < 8; ++h) { den[h] = 0.f; num[h] = 0.f; }

    if (sub == 0) {                       // self-loop
        #pragma unroll
        for (int h = 0; h < 8; ++h) {
            float e = fmaf(xd, cs[h], xd * cd[h]);
            e = e > 0.f ? e : LRELU_SLOPE * e;
            float ex = __expf(e);
            den[h] = ex; num[h] = ex * xd;
        }
    }
    int deg = cnt[n];
    int dcl = deg < K_SLAB ? deg : K_SLAB;
    for (int k = sub; k < dcl; k += 8) {
        float xs = x[colsrc[k * N + n]];
        #pragma unroll
        for (int h = 0; h < 8; ++h) {
            float e = fmaf(xs, cs[h], xd * cd[h]);
            e = e > 0.f ? e : LRELU_SLOPE * e;
            float ex = __expf(e);
            den[h] += ex; num[h] += ex * xs;
        }
    }
    if (deg > K_SLAB) {                   // overflow scan (empty in practice)
        int m = *ovfcnt; m = m < OVF_MAX ? m : OVF_MAX;
        for (int i = sub; i < m; i += 8) {
            if (ovfd[i] == n) {
                float xs = x[ovfs[i]];
                #pragma unroll
                for (int h = 0; h < 8; ++h) {
                    float e = fmaf(xs, cs[h], xd * cd[h]);
                    e = e > 0.f ? e : LRELU_SLOPE * e;
                    float ex = __expf(e);
                    den[h] += ex; num[h] += ex * xs;
                }
            }
        }
    }
    #pragma unroll
    for (int off = 1; off < 8; off <<= 1) {
        #pragma unroll
        for (int h = 0; h < 8; ++h) {
            den[h] += __shfl_xor(den[h], off);
            num[h] += __shfl_xor(num[h], off);
        }
    }
    float sh[8];
    #pragma unroll
    for (int h = 0; h < 8; ++h) sh[h] = num[h] / (den[h] + 1e-16f);

    const float4* W1v = (const float4*)sW1;
    const float4* B1v = (const float4*)sB1;
    const float4* W2v = (const float4*)sW2;
    float h20 = 0.f, h21 = 0.f;
    #pragma unroll
    for (int h = 0; h < 8; ++h) {
        float s = sh[h];
        #pragma unroll
        for (int j = 0; j < 2; ++j) {
            int q = h * 16 + sub * 2 + j;
            float4 a  = W1v[q];
            float4 b  = B1v[q];
            float4 wl = W2v[2 * q];
            float4 wh = W2v[2 * q + 1];
            float v0 = fmaxf(fmaf(a.x, s, b.x), 0.f);
            float v1 = fmaxf(fmaf(a.y, s, b.y), 0.f);
            float v2 = fmaxf(fmaf(a.z, s, b.z), 0.f);
            float v3 = fmaxf(fmaf(a.w, s, b.w), 0.f);
            h20 = fmaf(v0, wl.x, h20); h21 = fmaf(v0, wl.y, h21);
            h20 = fmaf(v1, wl.z, h20); h21 = fmaf(v1, wl.w, h21);
            h20 = fmaf(v2, wh.x, h20); h21 = fmaf(v2, wh.y, h21);
            h20 = fmaf(v3, wh.z, h20); h21 = fmaf(v3, wh.w, h21);
        }
    }
    #pragma unroll
    for (int off = 1; off < 8; off <<= 1) {
        h20 += __shfl_xor(h20, off);
        h21 += __shfl_xor(h21, off);
    }
    if (sub == 0) {
        float as_ = h20 * as2[0] + h21 * as2[1];
        float ad_ = h20 * ad2[0] + h21 * ad2[1];
        float4 o; o.x = h20; o.y = h21; o.z = as_; o.w = ad_;
        nodef[n] = o;
    }
}

// K3: layer-2 gather + log_softmax + mean reduction. 4 threads per node.
__global__ __launch_bounds__(256) void k_gather2(
        const int* __restrict__ cnt, const int* __restrict__ colsrc,
        const int* __restrict__ ovfcnt, const int* __restrict__ ovfd,
        const int* __restrict__ ovfs,
        const float4* __restrict__ nodef, const float* __restrict__ b2,
        float* __restrict__ out, int N) {
    int t = blockIdx.x * blockDim.x + threadIdx.x;
    int n = t >> 2, sub = t & 3;
    float l0 = 0.f, l1 = 0.f;
    if (n < N) {
        float4 fd = nodef[n];
        float den = 0.f, n0 = 0.f, n1 = 0.f;
        if (sub == 0) {                   // self-loop
            float e = fd.z + fd.w;
            e = e > 0.f ? e : LRELU_SLOPE * e;
            float ex = __expf(e);
            den = ex; n0 = ex * fd.x; n1 = ex * fd.y;
        }
        int deg = cnt[n];
        int dcl = deg < K_SLAB ? deg : K_SLAB;
        for (int k = sub; k < dcl; k += 4) {
            float4 fs = nodef[colsrc[k * N + n]];
            float e = fs.z + fd.w;
            e = e > 0.f ? e : LRELU_SLOPE * e;
            float ex = __expf(e);
            den += ex; n0 += ex * fs.x; n1 += ex * fs.y;
        }
        if (deg > K_SLAB) {
            int m = *ovfcnt; m = m < OVF_MAX ? m : OVF_MAX;
            for (int i = sub; i < m; i += 4) {
                if (ovfd[i] == n) {
                    float4 fs = nodef[ovfs[i]];
                    float e = fs.z + fd.w;
                    e = e > 0.f ? e : LRELU_SLOPE * e;
                    float ex = __expf(e);
                    den += ex; n0 += ex * fs.x; n1 += ex * fs.y;
                }
            }
        }
        #pragma unroll
        for (int off = 1; off < 4; off <<= 1) {
            den += __shfl_xor(den, off);
            n0  += __shfl_xor(n0, off);
            n1  += __shfl_xor(n1, off);
        }
        if (sub == 0) {
            float inv = 1.f / (den + 1e-16f);
            float o0 = n0 * inv + b2[0];
            float o1 = n1 * inv + b2[1];
            float m = fmaxf(o0, o1);
            float z0 = o0 - m, z1 = o1 - m;
            float lse = logf(__expf(z0) + __expf(z1));
            l0 = z0 - lse; l1 = z1 - lse;
        }
    }
    #pragma unroll
    for (int off = 32; off; off >>= 1) {
        l0 += __shfl_down(l0, off);
        l1 += __shfl_down(l1, off);
    }
    __shared__ float w0[4], w1[4];
    int wid = threadIdx.x >> 6, lane = threadIdx.x & 63;
    if (lane == 0) { w0[wid] = l0; w1[wid] = l1; }
    __syncthreads();
    if (threadIdx.x == 0) {
        float s0 = w0[0] + w0[1] + w0[2] + w0[3];
        float s1 = w1[0] + w1[1] + w1[2] + w1[3];
        float invN = 1.f / (float)N;
        atomicAdd(&out[0], s0 * invN);
        atomicAdd(&out[1], s1 * invN);
    }
}

extern "C" void kernel_launch(void* const* d_in, const int* in_sizes, int n_in,
                              void* d_out, int out_size, void* d_ws, size_t ws_size,
                              hipStream_t stream) {
    const float* x   = (const float*)d_in[0];
    const int*   ei  = (const int*)d_in[1];
    const float* W1  = (const float*)d_in[2];
    const float* as1 = (const float*)d_in[3];
    const float* ad1 = (const float*)d_in[4];
    const float* b1  = (const float*)d_in[5];
    const float* W2  = (const float*)d_in[6];
    const float* as2 = (const float*)d_in[7];
    const float* ad2 = (const float*)d_in[8];
    const float* b2  = (const float*)d_in[9];
    int N = in_sizes[0];       // 50000
    int E = in_sizes[1] / 2;   // 400000
    float* out = (float*)d_out;

    char* ws = (char*)d_ws;
    float4* nodef  = (float4*)ws;                    // N float4
    int*    cnt    = (int*)(ws + (size_t)N * 16);    // N
    int*    ovfcnt = cnt + N;                        // 1
    int*    colsrc = ovfcnt + 1;                     // K_SLAB*N
    int*    ovfd   = colsrc + (size_t)K_SLAB * N;    // OVF_MAX
    int*    ovfs   = ovfd + OVF_MAX;                 // OVF_MAX

    const int* esrc = ei;
    const int* edst = ei + E;

    // zero cnt + ovfcnt (one fill dispatch)
    hipMemsetAsync(cnt, 0, (size_t)(N + 1) * sizeof(int), stream);

    int items = (E + 3) / 4;
    int eb = (items + 255) / 256;
    hipLaunchKernelGGL(k_scatter, dim3(eb), dim3(256), 0, stream,
                       esrc, edst, cnt, colsrc, ovfcnt, ovfd, ovfs, out, E, N);

    int g1b = (8 * N + 255) / 256;
    hipLaunchKernelGGL(k_gather1, dim3(g1b), dim3(256), 0, stream,
                       cnt, colsrc, ovfcnt, ovfd, ovfs, x,
                       W1, as1, ad1, b1, W2, as2, ad2, nodef, N);

    int g2b = (4 * N + 255) / 256;
    hipLaunchKernelGGL(k_gather2, dim3(g2b), dim3(256), 0, stream,
                       cnt, colsrc, ovfcnt, ovfd, ovfs, nodef, b2, out, N);
}